// Round 1
// baseline (2019.680 us; speedup 1.0000x reference)
//
#include <hip/hip_runtime.h>
#include <math.h>

#define NEG_SLOPE 0.2f

__device__ __forceinline__ float wredmax(float v){
  #pragma unroll
  for (int o = 32; o; o >>= 1) v = fmaxf(v, __shfl_xor(v, o, 64));
  return v;
}
__device__ __forceinline__ float wredsum(float v){
  #pragma unroll
  for (int o = 32; o; o >>= 1) v += __shfl_xor(v, o, 64);
  return v;
}
__device__ __forceinline__ float lrelu(float x){ return x >= 0.f ? x : NEG_SLOPE * x; }

// ---- CSR construction ------------------------------------------------------
__global__ void k_deg_attr(const int* __restrict__ ei, const float* __restrict__ ea,
                           int* __restrict__ deg, float* __restrict__ loop_attr, int E){
  int idx = blockIdx.x * 256 + threadIdx.x;
  int e = idx >> 5, k = idx & 31;
  if (e >= E) return;
  int dst = ei[E + e];
  atomicAdd(&loop_attr[dst * 32 + k], ea[(size_t)e * 32 + k]);
  if (k == 0) atomicAdd(&deg[dst], 1);
}

__global__ void k_loop_div(float* __restrict__ loop_attr, const int* __restrict__ deg, int N){
  int idx = blockIdx.x * 256 + threadIdx.x;
  if (idx >= N * 32) return;
  float d = (float)max(deg[idx >> 5], 1);
  loop_attr[idx] /= d;
}

// row width = deg[n] + 1 (self loop).  N = 16384 = 256 * 64, single block scan.
__global__ void k_scan(const int* __restrict__ deg, int* __restrict__ row_start, int N){
  __shared__ int s[256];
  int t = threadIdx.x;
  int base = t * 64;
  int sum = 0;
  for (int i = 0; i < 64; ++i) sum += deg[base + i] + 1;
  s[t] = sum;
  __syncthreads();
  for (int off = 1; off < 256; off <<= 1){
    int v = (t >= off) ? s[t - off] : 0;
    __syncthreads();
    s[t] += v;
    __syncthreads();
  }
  int run = s[t] - sum;   // exclusive
  for (int i = 0; i < 64; ++i){ row_start[base + i] = run; run += deg[base + i] + 1; }
  if (t == 255) row_start[N] = run;
}

__global__ void k_csr_self(const int* __restrict__ row_start, int* __restrict__ csr_src,
                           int* __restrict__ pos_map, int N, int E){
  int n = blockIdx.x * 256 + threadIdx.x;
  if (n >= N) return;
  int p = row_start[n];
  csr_src[p] = n;          // self loop in slot 0
  pos_map[E + n] = p;
}

__global__ void k_csr_fill(const int* __restrict__ ei, const int* __restrict__ row_start,
                           int* __restrict__ fill, int* __restrict__ csr_src,
                           int* __restrict__ pos_map, int E){
  int e = blockIdx.x * 256 + threadIdx.x;
  if (e >= E) return;
  int dst = ei[E + e];
  int p = row_start[dst] + 1 + atomicAdd(&fill[dst], 1);
  csr_src[p] = ei[e];
  pos_map[e] = p;
}

// ---- fp32 GEMM: C[M,N] = A[M,K] @ B[K,N] + bias  (M%64==0, N%64==0, K%16==0)
__global__ __launch_bounds__(256) void k_gemm_bias(const float* __restrict__ A,
    const float* __restrict__ B, const float* __restrict__ bias, float* __restrict__ C,
    int M, int N, int K){
  __shared__ float As[16][64];
  __shared__ float Bs[16][64];
  int t = threadIdx.x;
  int bx = blockIdx.x, by = blockIdx.y;
  int tx = t & 15, ty = t >> 4;
  int la_r = t >> 2;            // 0..63   (m within tile)
  int la_c = (t & 3) << 2;      // 0,4,8,12 (k within tile)
  int lb_r = t >> 4;            // 0..15   (k within tile)
  int lb_c = (t & 15) << 2;     // 0..60   (n within tile)
  const float* Ap = A + (size_t)(by * 64 + la_r) * K + la_c;
  const float* Bp = B + (size_t)lb_r * N + bx * 64 + lb_c;
  float acc[4][4] = {};
  for (int k0 = 0; k0 < K; k0 += 16){
    float4 a4 = *(const float4*)(Ap + k0);
    float4 b4 = *(const float4*)(Bp + (size_t)k0 * N);
    __syncthreads();
    As[la_c + 0][la_r] = a4.x;
    As[la_c + 1][la_r] = a4.y;
    As[la_c + 2][la_r] = a4.z;
    As[la_c + 3][la_r] = a4.w;
    *(float4*)&Bs[lb_r][lb_c] = b4;
    __syncthreads();
    #pragma unroll
    for (int kk = 0; kk < 16; ++kk){
      float4 av = *(float4*)&As[kk][ty << 2];
      float4 bv = *(float4*)&Bs[kk][tx << 2];
      acc[0][0] += av.x * bv.x; acc[0][1] += av.x * bv.y; acc[0][2] += av.x * bv.z; acc[0][3] += av.x * bv.w;
      acc[1][0] += av.y * bv.x; acc[1][1] += av.y * bv.y; acc[1][2] += av.y * bv.z; acc[1][3] += av.y * bv.w;
      acc[2][0] += av.z * bv.x; acc[2][1] += av.z * bv.y; acc[2][2] += av.z * bv.z; acc[2][3] += av.z * bv.w;
      acc[3][0] += av.w * bv.x; acc[3][1] += av.w * bv.y; acc[3][2] += av.w * bv.z; acc[3][3] += av.w * bv.w;
    }
  }
  int m0 = by * 64 + (ty << 2);
  int n0 = bx * 64 + (tx << 2);
  float4 bi = *(const float4*)&bias[n0];
  #pragma unroll
  for (int i = 0; i < 4; ++i){
    float4 o = make_float4(acc[i][0] + bi.x, acc[i][1] + bi.y, acc[i][2] + bi.z, acc[i][3] + bi.w);
    *(float4*)&C[(size_t)(m0 + i) * N + n0] = o;
  }
}

// ---- edge logits: elog[pos] += sum_j att[j]*lrelu(xl[src][j]+xr[dst][j]+(ea@We)[j])
// j-chunked (256 wide, We chunk in LDS), 2 edges per wave, ea wave-uniform.
__global__ __launch_bounds__(256) void k_logit(const float* __restrict__ XL,
    const float* __restrict__ XR, const int* __restrict__ ei, const float* __restrict__ ea,
    const float* __restrict__ loop_attr, const float* __restrict__ We,
    const float* __restrict__ att, const int* __restrict__ pos_map,
    float* __restrict__ elog, int E, int Eaug, int FO){
  __shared__ float We_s[32 * 256];
  __shared__ float att_s[256];
  int t = threadIdx.x;
  int j0 = blockIdx.x << 8;
  for (int idx = t * 4; idx < 32 * 256; idx += 1024){
    int k = idx >> 8, jj = idx & 255;
    *(float4*)&We_s[idx] = *(const float4*)&We[(size_t)k * FO + j0 + jj];
  }
  att_s[t] = att[j0 + t];
  __syncthreads();
  int lane = t & 63;
  int wave = __builtin_amdgcn_readfirstlane(t >> 6);
  int w = blockIdx.y * 4 + wave;
  int nw = gridDim.y * 4;
  int jj = lane << 2;
  // Eaug is even; each wave takes pairs (e0, e0+1).
  for (int e0 = w * 2; e0 < Eaug; e0 += nw * 2){
    int e1 = e0 + 1;
    int s0, d0, s1, d1;
    const float *p0, *p1;
    if (e0 < E){ s0 = ei[e0]; d0 = ei[E + e0]; p0 = ea + (size_t)e0 * 32; }
    else       { s0 = d0 = e0 - E;             p0 = loop_attr + (size_t)(e0 - E) * 32; }
    if (e1 < E){ s1 = ei[e1]; d1 = ei[E + e1]; p1 = ea + (size_t)e1 * 32; }
    else       { s1 = d1 = e1 - E;             p1 = loop_attr + (size_t)(e1 - E) * 32; }
    float a0[32], a1[32];
    #pragma unroll
    for (int k = 0; k < 32; ++k){ a0[k] = p0[k]; a1[k] = p1[k]; }
    float4 l0 = *(const float4*)&XL[(size_t)s0 * FO + j0 + jj];
    float4 r0 = *(const float4*)&XR[(size_t)d0 * FO + j0 + jj];
    float4 l1 = *(const float4*)&XL[(size_t)s1 * FO + j0 + jj];
    float4 r1 = *(const float4*)&XR[(size_t)d1 * FO + j0 + jj];
    float4 v0 = make_float4(l0.x + r0.x, l0.y + r0.y, l0.z + r0.z, l0.w + r0.w);
    float4 v1 = make_float4(l1.x + r1.x, l1.y + r1.y, l1.z + r1.z, l1.w + r1.w);
    #pragma unroll
    for (int k = 0; k < 32; ++k){
      float4 wv = *(float4*)&We_s[k * 256 + jj];
      v0.x += a0[k] * wv.x; v0.y += a0[k] * wv.y; v0.z += a0[k] * wv.z; v0.w += a0[k] * wv.w;
      v1.x += a1[k] * wv.x; v1.y += a1[k] * wv.y; v1.z += a1[k] * wv.z; v1.w += a1[k] * wv.w;
    }
    float4 at = *(float4*)&att_s[jj];
    float t0 = at.x * lrelu(v0.x) + at.y * lrelu(v0.y) + at.z * lrelu(v0.z) + at.w * lrelu(v0.w);
    float t1 = at.x * lrelu(v1.x) + at.y * lrelu(v1.y) + at.z * lrelu(v1.z) + at.w * lrelu(v1.w);
    t0 = wredsum(t0);
    t1 = wredsum(t1);
    if (lane == 0){
      atomicAdd(&elog[pos_map[e0]], t0);
      atomicAdd(&elog[pos_map[e1]], t1);
    }
  }
}

// ---- per-dst softmax + weighted aggregation (one wave per node) ------------
template<int CH>
__global__ __launch_bounds__(256) void k_aggregate(const float* __restrict__ XL,
    const float* __restrict__ elog, const int* __restrict__ csr_src,
    const int* __restrict__ row_start, const float* __restrict__ bc,
    float* __restrict__ out, int FO){
  int lane = threadIdx.x & 63;
  int wave = __builtin_amdgcn_readfirstlane(threadIdx.x >> 6);
  int n = blockIdx.x * 4 + wave;
  int rs = row_start[n], re = row_start[n + 1];
  int cnt = re - rs;
  float m = -1e30f;
  for (int i = lane; i < cnt; i += 64) m = fmaxf(m, elog[rs + i]);
  m = wredmax(m);
  float s = 0.f;
  for (int i = lane; i < cnt; i += 64) s += __expf(elog[rs + i] - m);
  s = wredsum(s);
  float inv = 1.f / s;
  float4 acc[CH];
  #pragma unroll
  for (int c = 0; c < CH; ++c) acc[c] = make_float4(0.f, 0.f, 0.f, 0.f);
  int jj = lane << 2;
  for (int i = 0; i < cnt; ++i){
    float wgt = __expf(elog[rs + i] - m) * inv;
    int src = csr_src[rs + i];
    const float* xp = XL + (size_t)src * FO;
    #pragma unroll
    for (int c = 0; c < CH; ++c){
      float4 x4 = *(const float4*)&xp[c * 256 + jj];
      acc[c].x += wgt * x4.x; acc[c].y += wgt * x4.y;
      acc[c].z += wgt * x4.z; acc[c].w += wgt * x4.w;
    }
  }
  #pragma unroll
  for (int c = 0; c < CH; ++c){
    float4 b4 = *(const float4*)&bc[c * 256 + jj];
    float4 o = make_float4(fmaxf(acc[c].x + b4.x, 0.f), fmaxf(acc[c].y + b4.y, 0.f),
                           fmaxf(acc[c].z + b4.z, 0.f), fmaxf(acc[c].w + b4.w, 0.f));
    *(float4*)&out[(size_t)n * FO + c * 256 + jj] = o;
  }
}

// ---- pooling + head --------------------------------------------------------
__global__ void k_pool(const float* __restrict__ H, const int* __restrict__ batch,
                       float* __restrict__ psum, float* __restrict__ pcnt){
  int n = blockIdx.x;
  int j = threadIdx.x;
  int g = batch[n];
  atomicAdd(&psum[g * 256 + j], H[(size_t)n * 256 + j]);
  if (j == 0) atomicAdd(&pcnt[g], 1.f);
}

__global__ void k_fc1(const float* __restrict__ psum, const float* __restrict__ pcnt,
                      const float* __restrict__ w, const float* __restrict__ b,
                      float* __restrict__ z){
  int idx = blockIdx.x * 256 + threadIdx.x;
  if (idx >= 128 * 64) return;
  int g = idx >> 6, j = idx & 63;
  float acc = 0.f;
  for (int k = 0; k < 256; ++k) acc += psum[g * 256 + k] * w[k * 64 + j];
  z[idx] = acc / fmaxf(pcnt[g], 1.f) + b[j];
}

__global__ void k_head(const float* __restrict__ z, const float* __restrict__ bn_g,
                       const float* __restrict__ bn_b, const float* __restrict__ w2,
                       const float* __restrict__ b2, float* __restrict__ out){
  __shared__ float mu_s[64], is_s[64];
  int t = threadIdx.x;  // 128 threads
  if (t < 64){
    float mu = 0.f, m2 = 0.f;
    for (int g = 0; g < 128; ++g){ float v = z[g * 64 + t]; mu += v; m2 += v * v; }
    mu /= 128.f; m2 /= 128.f;
    float var = m2 - mu * mu;
    mu_s[t] = mu;
    is_s[t] = rsqrtf(var + 1e-5f);
  }
  __syncthreads();
  float o = b2[0];
  for (int j = 0; j < 64; ++j){
    float v = (z[t * 64 + j] - mu_s[j]) * is_s[j] * bn_g[j] + bn_b[j];
    o += fmaxf(v, 0.f) * w2[j];
  }
  out[t] = o;
}

extern "C" void kernel_launch(void* const* d_in, const int* in_sizes, int n_in,
                              void* d_out, int out_size, void* d_ws, size_t ws_size,
                              hipStream_t stream){
  const int N = 16384, E = 131072, Eaug = E + N, NG = 128;
  const float* x     = (const float*)d_in[0];
  const int*   ei    = (const int*)  d_in[1];
  const float* ea    = (const float*)d_in[2];
  const int*   batch = (const int*)  d_in[3];
  const float* Wl[3]  = {(const float*)d_in[4],  (const float*)d_in[11], (const float*)d_in[18]};
  const float* bl[3]  = {(const float*)d_in[5],  (const float*)d_in[12], (const float*)d_in[19]};
  const float* Wr[3]  = {(const float*)d_in[6],  (const float*)d_in[13], (const float*)d_in[20]};
  const float* br[3]  = {(const float*)d_in[7],  (const float*)d_in[14], (const float*)d_in[21]};
  const float* We[3]  = {(const float*)d_in[8],  (const float*)d_in[15], (const float*)d_in[22]};
  const float* att[3] = {(const float*)d_in[9],  (const float*)d_in[16], (const float*)d_in[23]};
  const float* bc[3]  = {(const float*)d_in[10], (const float*)d_in[17], (const float*)d_in[24]};
  const float* fc1_w = (const float*)d_in[25];
  const float* fc1_b = (const float*)d_in[26];
  const float* bn_g  = (const float*)d_in[27];
  const float* bn_b  = (const float*)d_in[28];
  const float* fc2_w = (const float*)d_in[29];
  const float* fc2_b = (const float*)d_in[30];
  float* out = (float*)d_out;

  char* wsb = (char*)d_ws;
  size_t off = 0;
  auto alloc = [&](size_t bytes) -> char* {
    char* p = wsb + off;
    off = (off + bytes + 255) & ~(size_t)255;
    return p;
  };
  int*   deg       = (int*)  alloc((size_t)N * 4);
  int*   fill      = (int*)  alloc((size_t)N * 4);
  int*   row_start = (int*)  alloc((size_t)(N + 1) * 4);
  float* loop_attr = (float*)alloc((size_t)N * 32 * 4);
  int*   csr_src   = (int*)  alloc((size_t)Eaug * 4);
  int*   pos_map   = (int*)  alloc((size_t)Eaug * 4);
  float* elog      = (float*)alloc((size_t)Eaug * 4);
  float* XL        = (float*)alloc((size_t)N * 1024 * 4);
  float* XR        = (float*)alloc((size_t)N * 1024 * 4);
  float* buf1      = (float*)alloc((size_t)N * 512 * 4);   // L1 out (512) / L3 out (256)
  float* buf2      = (float*)alloc((size_t)N * 1024 * 4);  // L2 out
  float* psum      = (float*)alloc((size_t)NG * 256 * 4);
  float* pcnt      = (float*)alloc((size_t)NG * 4);
  float* zbuf      = (float*)alloc((size_t)NG * 64 * 4);

  hipMemsetAsync(deg, 0, (size_t)N * 4, stream);
  hipMemsetAsync(fill, 0, (size_t)N * 4, stream);
  hipMemsetAsync(loop_attr, 0, (size_t)N * 32 * 4, stream);
  hipMemsetAsync(psum, 0, (size_t)NG * 256 * 4, stream);
  hipMemsetAsync(pcnt, 0, (size_t)NG * 4, stream);

  k_deg_attr<<<(E * 32) / 256, 256, 0, stream>>>(ei, ea, deg, loop_attr, E);
  k_loop_div<<<(N * 32) / 256, 256, 0, stream>>>(loop_attr, deg, N);
  k_scan<<<1, 256, 0, stream>>>(deg, row_start, N);
  k_csr_self<<<N / 256, 256, 0, stream>>>(row_start, csr_src, pos_map, N, E);
  k_csr_fill<<<E / 256, 256, 0, stream>>>(ei, row_start, fill, csr_src, pos_map, E);

  const int fin[3] = {256, 512, 1024};
  const int fo[3]  = {512, 1024, 256};
  float* outbuf[3] = {buf1, buf2, buf1};
  const float* Xin = x;
  for (int L = 0; L < 3; ++L){
    int FI = fin[L], FO = fo[L];
    dim3 ggrid(FO / 64, N / 64);
    k_gemm_bias<<<ggrid, 256, 0, stream>>>(Xin, Wl[L], bl[L], XL, N, FO, FI);
    k_gemm_bias<<<ggrid, 256, 0, stream>>>(Xin, Wr[L], br[L], XR, N, FO, FI);
    hipMemsetAsync(elog, 0, (size_t)Eaug * 4, stream);
    dim3 lgrid(FO / 256, 2048);
    k_logit<<<lgrid, 256, 0, stream>>>(XL, XR, ei, ea, loop_attr, We[L], att[L],
                                       pos_map, elog, E, Eaug, FO);
    if (FO == 256)
      k_aggregate<1><<<N / 4, 256, 0, stream>>>(XL, elog, csr_src, row_start, bc[L], outbuf[L], FO);
    else if (FO == 512)
      k_aggregate<2><<<N / 4, 256, 0, stream>>>(XL, elog, csr_src, row_start, bc[L], outbuf[L], FO);
    else
      k_aggregate<4><<<N / 4, 256, 0, stream>>>(XL, elog, csr_src, row_start, bc[L], outbuf[L], FO);
    Xin = outbuf[L];
  }
  k_pool<<<N, 256, 0, stream>>>(buf1, batch, psum, pcnt);
  k_fc1<<<32, 256, 0, stream>>>(psum, pcnt, fc1_w, fc1_b, zbuf);
  k_head<<<1, 128, 0, stream>>>(zbuf, bn_g, bn_b, fc2_w, fc2_b, out);
}